// Round 10
// baseline (552.665 us; speedup 1.0000x reference)
//
#include <hip/hip_runtime.h>
#include <stdint.h>

// SimpleGCN, f32 in / f32 out. Round 10: barrier-free direct-from-global
// fragment GEMMs (no LDS staging, no __syncthreads in the K-loop; per-use
// fine-grained vmcnt waits + 2-stage register pipeline hide latency).
//   conv: Fs,Ft,W1 -> f16; W2 -> bf16
//   G2 : S = Fsf@Ftf^T (f16 MFMA); P~=exp(S-100)->bf16 [8192][8192] + rowsum partials
//   FIN: invl = 1/sum rsp
//   GY1: Y1T = W1f@Fsf^T (f16) -> bf16 [256][8192]
//   F1 : pp[z] = invl(.)(P~ @ Y1) (bf16), split-K=4, f16 partials
//   C1 : x1 = sum4(pp) -> f32 d_out + bf16 x1h
//   GY2: Y2T = W2h@x1h^T (bf16) -> bf16 [128][8192]
//   F2 : pp[z] = invl(.)(P~ @ Y2), split-K=8, f16 partials
//   C2 : x2 = sum8(pp) -> f32 d_out
// NT GEMMs: C[M,N]=A[M,K]*B[N,K]^T, 128x128 tile, 4 waves x 4x4 MFMA 16x16x32.
// Fragment loads: lane(t,quad) reads A[row(t)][k0+quad*8..+8] = 16B; the 4
// quads of each t cover 64 contiguous bytes -> 16 full cache lines per instr.
// Epilogue coords from runtime MFMA layout probe (rmap/cmap).

typedef unsigned short u16;
typedef short bf16x8 __attribute__((ext_vector_type(8)));
typedef _Float16 f16x8 __attribute__((ext_vector_type(8)));
typedef float f32x4 __attribute__((ext_vector_type(4)));

#define EPI_PEXP   0   // exp(acc-100) -> bf16 P + rowsum partials (aux=rsp)
#define EPI_STOREB 1   // store bf16 C
#define EPI_PARTH  2   // store f16 invl-scaled partial at zoff (aux=invl)

__device__ __forceinline__ u16 f2bf(float f) {
  unsigned u = __float_as_uint(f);
  u += 0x7fffu + ((u >> 16) & 1u);
  return (u16)(u >> 16);
}
__device__ __forceinline__ u16 f2h(float f) {
  union { _Float16 h; u16 u; } cv; cv.h = (_Float16)f; return cv.u;
}
__device__ __forceinline__ float h2f(u16 u) {
  union { u16 u; _Float16 h; } cv; cv.u = u; return (float)cv.h;
}

// ---------------------------------------------------------------------------
__global__ void probe_layout(int* __restrict__ rmap, int* __restrict__ cmap) {
  const int lane = threadIdx.x & 63;
  const int t = lane & 15, quad = lane >> 4;
  bf16x8 avt, av1;
  const u16 bt = f2bf((float)t), b1 = 0x3f80;
#pragma unroll
  for (int j = 0; j < 8; ++j) { ((u16*)&avt)[j] = bt; ((u16*)&av1)[j] = b1; }
  f32x4 z = {0.f, 0.f, 0.f, 0.f};
  f32x4 r1 = __builtin_amdgcn_mfma_f32_16x16x32_bf16(avt, av1, z, 0, 0, 0);
  f32x4 r2 = __builtin_amdgcn_mfma_f32_16x16x32_bf16(av1, avt, z, 0, 0, 0);
  if (threadIdx.x < 64) {
#pragma unroll
    for (int e = 0; e < 4; ++e) {
      int r = (int)(r1[e] * 0.03125f + 0.5f);
      int c = (int)(r2[e] * 0.03125f + 0.5f);
      if (r < 0 || r > 15) r = quad * 4 + e;
      if (c < 0 || c > 15) c = t;
      rmap[lane * 4 + e] = r;
      cmap[lane * 4 + e] = c;
    }
  }
}

// ---------------------------------------------------------------------------
__global__ __launch_bounds__(256) void conv_all(
    const float* __restrict__ Fs, const float* __restrict__ Ft,
    const float* __restrict__ W1, const float* __restrict__ W2,
    u16* __restrict__ Fsf, u16* __restrict__ Ftf,
    u16* __restrict__ W1f, u16* __restrict__ W2h) {
  const int bx = blockIdx.x, tid = threadIdx.x;
  if (bx < 2048) {
    for (int i = bx * 256 + tid; i < 4194304; i += 2048 * 256) Fsf[i] = f2h(Fs[i]);
  } else if (bx < 4096) {
    for (int i = (bx - 2048) * 256 + tid; i < 4194304; i += 2048 * 256) Ftf[i] = f2h(Ft[i]);
  } else if (bx < 4160) {
    for (int i = (bx - 4096) * 256 + tid; i < 131072; i += 64 * 256) W1f[i] = f2h(W1[i]);
  } else {
    for (int i = (bx - 4160) * 256 + tid; i < 32768; i += 16 * 256) W2h[i] = f2bf(W2[i]);
  }
}

// ---------------------------------------------------------------------------
__device__ __forceinline__ void load8(bf16x8 a[4], bf16x8 b[4],
                                      const u16* const pA[4],
                                      const u16* const pB[4], int s) {
#pragma unroll
  for (int i = 0; i < 4; ++i) {
    a[i] = *(const bf16x8*)(pA[i] + s * 32);
    b[i] = *(const bf16x8*)(pB[i] + s * 32);
  }
}

template <int F16>
__device__ __forceinline__ void mfma16(f32x4 acc[4][4],
                                       const bf16x8 a[4], const bf16x8 b[4]) {
#pragma unroll
  for (int mi = 0; mi < 4; ++mi)
#pragma unroll
    for (int ni = 0; ni < 4; ++ni) {
      if constexpr (F16)
        acc[mi][ni] = __builtin_amdgcn_mfma_f32_16x16x32_f16(
            __builtin_bit_cast(f16x8, a[mi]), __builtin_bit_cast(f16x8, b[ni]),
            acc[mi][ni], 0, 0, 0);
      else
        acc[mi][ni] = __builtin_amdgcn_mfma_f32_16x16x32_bf16(
            a[mi], b[ni], acc[mi][ni], 0, 0, 0);
    }
}

// ---------------------------------------------------------------------------
// Direct-load NT GEMM, 128x128 tile, BK=32 steps, 2-stage register pipeline.
// ---------------------------------------------------------------------------
template <int EPI, int F16>
__global__ __launch_bounds__(256) void gemm_direct(
    const u16* __restrict__ A, const u16* __restrict__ B,
    int K, int Kc, int N,
    u16* __restrict__ outp, float* __restrict__ aux,
    const int* __restrict__ rmap, const int* __restrict__ cmap) {
  __shared__ float lrs[128][2];   // PEXP only

  const int tid = threadIdx.x;
  const int wave = tid >> 6, lane = tid & 63;
  const int quad = lane >> 4, t = lane & 15;
  const int bm = blockIdx.y * 128, bn = blockIdx.x * 128;
  const int wm = (wave & 1) * 64, wn = (wave >> 1) * 64;
  const int koff = blockIdx.z * Kc;

  f32x4 acc[4][4];
#pragma unroll
  for (int i = 0; i < 4; ++i)
#pragma unroll
    for (int j = 0; j < 4; ++j) acc[i][j] = (f32x4){0.f, 0.f, 0.f, 0.f};

  const u16* pA[4];
  const u16* pB[4];
#pragma unroll
  for (int i = 0; i < 4; ++i) {
    pA[i] = A + (size_t)(bm + wm + i * 16 + t) * K + koff + quad * 8;
    pB[i] = B + (size_t)(bn + wn + i * 16 + t) * K + koff + quad * 8;
  }

  const int nsteps = Kc >> 5;   // even for all call sites (>=8)
  bf16x8 a0[4], b0[4], a1[4], b1[4];

  load8(a0, b0, pA, pB, 0);
  for (int s = 0; s < nsteps - 2; s += 2) {
    load8(a1, b1, pA, pB, s + 1);
    mfma16<F16>(acc, a0, b0);
    load8(a0, b0, pA, pB, s + 2);
    mfma16<F16>(acc, a1, b1);
  }
  load8(a1, b1, pA, pB, nsteps - 1);
  mfma16<F16>(acc, a0, b0);
  mfma16<F16>(acc, a1, b1);

  int rl[4], cl[4];
#pragma unroll
  for (int e = 0; e < 4; ++e) {
    rl[e] = rmap[lane * 4 + e];
    cl[e] = cmap[lane * 4 + e];
  }

  if constexpr (EPI == EPI_PEXP) {
#pragma unroll
    for (int mi = 0; mi < 4; ++mi)
#pragma unroll
      for (int e = 0; e < 4; ++e) {
        const int rloc = wm + mi * 16 + rl[e];
        const int row = bm + rloc;
        float s = 0.f;
#pragma unroll
        for (int ni = 0; ni < 4; ++ni) {
          float p = __expf(acc[mi][ni][e] - 100.0f);
          s += p;
          outp[(size_t)row * N + (bn + wn + ni * 16 + cl[e])] = f2bf(p);
        }
        s += __shfl_xor(s, 1, 64);
        s += __shfl_xor(s, 2, 64);
        s += __shfl_xor(s, 4, 64);
        s += __shfl_xor(s, 8, 64);
        if (t == 0) lrs[rloc][wave >> 1] = s;
      }
    __syncthreads();
    if (tid < 128)
      aux[(size_t)blockIdx.x * 8192 + bm + tid] = lrs[tid][0] + lrs[tid][1];
  } else {
    const size_t zoff = (size_t)blockIdx.z * ((size_t)gridDim.y * 128) * N;
#pragma unroll
    for (int mi = 0; mi < 4; ++mi)
#pragma unroll
      for (int e = 0; e < 4; ++e) {
        const int row = bm + wm + mi * 16 + rl[e];
        const float sc = (EPI == EPI_PARTH) ? aux[row] : 1.0f;
#pragma unroll
        for (int ni = 0; ni < 4; ++ni) {
          const size_t idx = (size_t)row * N + (bn + wn + ni * 16 + cl[e]);
          if (EPI == EPI_PARTH) outp[zoff + idx] = f2h(acc[mi][ni][e] * sc);
          else                  outp[idx] = f2bf(acc[mi][ni][e]);
        }
      }
  }
}

// ---------------------------------------------------------------------------
__global__ __launch_bounds__(256) void finalize_invl(
    const float* __restrict__ rsp, float* __restrict__ invl) {
  const int row = blockIdx.x * 256 + threadIdx.x;
  float s = 0.f;
#pragma unroll 8
  for (int b = 0; b < 64; ++b) s += rsp[(size_t)b * 8192 + row];
  invl[row] = 1.0f / s;
}

__global__ __launch_bounds__(256) void combine1(
    const u16* __restrict__ pp, const float* __restrict__ invl,
    float* __restrict__ x1f, u16* __restrict__ x1h) {
  const int row = blockIdx.x, j = threadIdx.x;
  const size_t i = (size_t)row * 256 + j;
  const float v = h2f(pp[i]) + h2f(pp[2097152 + i]) +
                  h2f(pp[4194304 + i]) + h2f(pp[6291456 + i]);
  x1f[i] = v;
  x1h[i] = f2bf(v);
}

__global__ __launch_bounds__(128) void combine2(
    const u16* __restrict__ pp, const float* __restrict__ invl,
    float* __restrict__ x2f) {
  const int row = blockIdx.x, j = threadIdx.x;
  const size_t i = (size_t)row * 128 + j;
  float s = 0.f;
#pragma unroll
  for (int z = 0; z < 8; ++z) s += h2f(pp[(size_t)z * 1048576 + i]);
  x2f[i] = s;
}

// ---------------------------------------------------------------------------
extern "C" void kernel_launch(void* const* d_in, const int* in_sizes, int n_in,
                              void* d_out, int out_size, void* d_ws, size_t ws_size,
                              hipStream_t stream) {
  const float* Fs = (const float*)d_in[0];   // [8192][512]
  const float* Ft = (const float*)d_in[1];   // [8192][512]
  const float* W1 = (const float*)d_in[2];   // [256][512]
  const float* W2 = (const float*)d_in[3];   // [128][256]

  char* ws = (char*)d_ws;                    // extent <= 168134656 (proven r5-r9)
  u16*   P    = (u16*)(ws);                  // [8192][8192] bf16, 0..128MiB
  u16*   Fsf  = (u16*)(ws + 134217728);      // 8MiB f16 (dead after GY1)
  u16*   Ftf  = (u16*)(ws + 142606336);      // 8MiB f16 (dead after G2)
  u16*   pp   = (u16*)(ws + 134217728);      // 16MiB f16 partials (born F1)
  float* rsp  = (float*)(ws + 150994944);    // [64][8192] f32 2MiB (dead after FIN)
  u16*   Y1T  = (u16*)(ws + 153091200);      // [256][8192] 4MiB
  u16*   x1h  = (u16*)(ws + 157286400);      // [8192][256] 4MiB
  u16*   Y2T  = (u16*)(ws + 161480704);      // [128][8192] 2MiB
  float* invl = (float*)(ws + 163577856);    // [8192]
  int*   rmap = (int*)  (ws + 163610624);
  int*   cmap = (int*)  (ws + 163611648);
  u16*   W1f  = (u16*)(ws + 163612672);      // [256][512] f16 256KiB
  u16*   W2h  = (u16*)(ws + 163874816);      // [128][256] bf16 64KiB -> 163938816

  float* x1f = (float*)d_out;                // [8192][256]
  float* x2f = (float*)d_out + 2097152;      // [8192][128]

  dim3 blk(256);
  probe_layout<<<1, 64, 0, stream>>>(rmap, cmap);
  conv_all<<<4176, blk, 0, stream>>>(Fs, Ft, W1, W2, Fsf, Ftf, W1f, W2h);
  // G2: P~ = exp(f16 S - 100) + fused row-sum partials
  gemm_direct<EPI_PEXP, 1><<<dim3(64, 64), blk, 0, stream>>>(
      Fsf, Ftf, 512, 512, 8192, P, rsp, rmap, cmap);
  finalize_invl<<<32, blk, 0, stream>>>(rsp, invl);
  // GY1: Y1T = W1f @ Fsf^T (f16)
  gemm_direct<EPI_STOREB, 1><<<dim3(64, 2), blk, 0, stream>>>(
      W1f, Fsf, 512, 512, 8192, Y1T, nullptr, rmap, cmap);
  // F1: pp[z] = invl(.)(P~ @ Y1), split-K=4 (Kc=2048)
  gemm_direct<EPI_PARTH, 0><<<dim3(2, 64, 4), blk, 0, stream>>>(
      P, Y1T, 8192, 2048, 256, pp, invl, rmap, cmap);
  combine1<<<8192, blk, 0, stream>>>(pp, invl, x1f, x1h);
  // GY2: Y2T = W2h @ x1h^T (bf16)
  gemm_direct<EPI_STOREB, 0><<<dim3(64, 1), blk, 0, stream>>>(
      W2h, x1h, 256, 256, 8192, Y2T, nullptr, rmap, cmap);
  // F2: pp[z] = invl(.)(P~ @ Y2), split-K=8 (Kc=1024)
  gemm_direct<EPI_PARTH, 0><<<dim3(1, 64, 8), blk, 0, stream>>>(
      P, Y2T, 8192, 1024, 128, pp, invl, rmap, cmap);
  combine2<<<8192, dim3(128), 0, stream>>>(pp, invl, x2f);
}

// Round 11
// 276.624 us; speedup vs baseline: 1.9979x; 1.9979x over previous
//
#include <hip/hip_runtime.h>
#include <stdint.h>

// SimpleGCN, f32 in / f32 out. Round 11 = r9 (best, 308us) with G2 retiled to
// 256x128 (512 thr, 8 waves): halves per-CU barrier-iterations, 1.33x less
// staging, same MFMA order (bit-identical absmax). r10's direct-load GEMM was
// latency-starved (MfmaUtil 10%) -> reverted to DMA staging everywhere.
//   conv: Fs,Ft,W1 -> f16; W2 -> bf16
//   G2 : S = Fsf@Ftf^T (f16 MFMA); P~=exp(S-100)->bf16 [8192][8192] + rowsum partials
//   FIN: invl = 1/sum rsp
//   GY1: Y1T = W1f@Fsf^T (f16) -> bf16 [256][8192]
//   F1 : pp[z] = invl(.)(P~ @ Y1) (bf16), split-K=4, f16 partials
//   C1 : x1 = sum4(pp) -> f32 d_out + bf16 x1h
//   GY2: Y2T = W2h@x1h^T (bf16) -> bf16 [128][8192]
//   F2 : pp[z] = invl(.)(P~ @ Y2), split-K=8, f16 partials
//   C2 : x2 = sum8(pp) -> f32 d_out
// NT GEMMs, BK=64, LDS rows 128B + 16B-chunk swizzle c^=swz8(r) (spreads the
// 128B-row-stride ds_read bank degeneracy). Epilogue coords from runtime MFMA
// layout probe (rmap/cmap).

typedef unsigned short u16;
typedef short bf16x8 __attribute__((ext_vector_type(8)));
typedef _Float16 f16x8 __attribute__((ext_vector_type(8)));
typedef float f32x4 __attribute__((ext_vector_type(4)));

#define EPI_STOREB 0   // store bf16 C at idx
#define EPI_PARTH  1   // store f16 invl-scaled partial at zoff+idx

__device__ __forceinline__ u16 f2bf(float f) {
  unsigned u = __float_as_uint(f);
  u += 0x7fffu + ((u >> 16) & 1u);
  return (u16)(u >> 16);
}
__device__ __forceinline__ u16 f2h(float f) {
  union { _Float16 h; u16 u; } cv; cv.h = (_Float16)f; return cv.u;
}
__device__ __forceinline__ float h2f(u16 u) {
  union { u16 u; _Float16 h; } cv; cv.u = u; return (float)cv.h;
}
__device__ __forceinline__ int swz8(int r) { return (r ^ (r >> 3)) & 7; }

__device__ __forceinline__ void async16(const void* g, void* lds) {
  __builtin_amdgcn_global_load_lds(
      (const __attribute__((address_space(1))) unsigned int*)g,
      (__attribute__((address_space(3))) unsigned int*)lds, 16, 0, 0);
}

// ---------------------------------------------------------------------------
__global__ void probe_layout(int* __restrict__ rmap, int* __restrict__ cmap) {
  const int lane = threadIdx.x & 63;
  const int t = lane & 15, quad = lane >> 4;
  bf16x8 avt, av1;
  const u16 bt = f2bf((float)t), b1 = 0x3f80;
#pragma unroll
  for (int j = 0; j < 8; ++j) { ((u16*)&avt)[j] = bt; ((u16*)&av1)[j] = b1; }
  f32x4 z = {0.f, 0.f, 0.f, 0.f};
  f32x4 r1 = __builtin_amdgcn_mfma_f32_16x16x32_bf16(avt, av1, z, 0, 0, 0);
  f32x4 r2 = __builtin_amdgcn_mfma_f32_16x16x32_bf16(av1, avt, z, 0, 0, 0);
  if (threadIdx.x < 64) {
#pragma unroll
    for (int e = 0; e < 4; ++e) {
      int r = (int)(r1[e] * 0.03125f + 0.5f);
      int c = (int)(r2[e] * 0.03125f + 0.5f);
      if (r < 0 || r > 15) r = quad * 4 + e;
      if (c < 0 || c > 15) c = t;
      rmap[lane * 4 + e] = r;
      cmap[lane * 4 + e] = c;
    }
  }
}

// ---------------------------------------------------------------------------
__global__ __launch_bounds__(256) void conv_all(
    const float* __restrict__ Fs, const float* __restrict__ Ft,
    const float* __restrict__ W1, const float* __restrict__ W2,
    u16* __restrict__ Fsf, u16* __restrict__ Ftf,
    u16* __restrict__ W1f, u16* __restrict__ W2h) {
  const int bx = blockIdx.x, tid = threadIdx.x;
  if (bx < 2048) {
    for (int i = bx * 256 + tid; i < 4194304; i += 2048 * 256) Fsf[i] = f2h(Fs[i]);
  } else if (bx < 4096) {
    for (int i = (bx - 2048) * 256 + tid; i < 4194304; i += 2048 * 256) Ftf[i] = f2h(Ft[i]);
  } else if (bx < 4160) {
    for (int i = (bx - 4096) * 256 + tid; i < 131072; i += 64 * 256) W1f[i] = f2h(W1[i]);
  } else {
    for (int i = (bx - 4160) * 256 + tid; i < 32768; i += 16 * 256) W2h[i] = f2bf(W2[i]);
  }
}

// ---------------------------------------------------------------------------
// G2: f16 NT GEMM, 256x128 tile, 512 threads (8 waves of 64x64), BK=64,
// swizzled LDS; exp epilogue + fused row-sum partials.
// ---------------------------------------------------------------------------
__global__ __launch_bounds__(512) void gemm_pexp_f16_256(
    const u16* __restrict__ A, const u16* __restrict__ B, int K, int N,
    u16* __restrict__ P, float* __restrict__ rsp,
    const int* __restrict__ rmap, const int* __restrict__ cmap) {
  __shared__ __align__(16) u16 lA[256 * 64];   // 32 KB, rows of 128 B
  __shared__ __align__(16) u16 lB[128 * 64];   // 16 KB
  __shared__ float lrs[256][2];

  const int tid = threadIdx.x;
  const int wave = tid >> 6, lane = tid & 63;
  const int quad = lane >> 4, t = lane & 15;
  const int bm = blockIdx.y * 256, bn = blockIdx.x * 128;
  const int wm = (wave & 3) * 64, wn = (wave >> 2) * 64;

  f32x4 acc[4][4];
#pragma unroll
  for (int i = 0; i < 4; ++i)
#pragma unroll
    for (int j = 0; j < 4; ++j) acc[i][j] = (f32x4){0.f, 0.f, 0.f, 0.f};

  // staging: 512 thr x 16B = 8 KB/call. A: 4 calls (rows j*64+(tid>>3));
  // B: 2 calls. chunk slot tid&7; source chunk xor-swizzled.
  const int srow = tid >> 3, schk = tid & 7;
  const u16* pA[4]; const u16* pB[2];
#pragma unroll
  for (int j = 0; j < 4; ++j) {
    const int r = j * 64 + srow;
    pA[j] = A + (size_t)(bm + r) * K + (schk ^ swz8(r)) * 8;
  }
#pragma unroll
  for (int j = 0; j < 2; ++j) {
    const int r = j * 64 + srow;
    pB[j] = B + (size_t)(bn + r) * K + (schk ^ swz8(r)) * 8;
  }

  int aoffx[4], boffx[4];
#pragma unroll
  for (int i = 0; i < 4; ++i) {
    const int rm = wm + i * 16 + t;
    aoffx[i] = rm * 128 + (swz8(rm) << 4);
    const int rn = wn + i * 16 + t;
    boffx[i] = rn * 128 + (swz8(rn) << 4);
  }
  const int sq0 = quad << 4, sq1 = (quad << 4) | 64;

  for (int k0 = 0; k0 < K; k0 += 64) {
#pragma unroll
    for (int j = 0; j < 4; ++j) {
      async16(pA[j], (char*)lA + j * 8192 + wave * 1024);
      pA[j] += 64;
    }
#pragma unroll
    for (int j = 0; j < 2; ++j) {
      async16(pB[j], (char*)lB + j * 8192 + wave * 1024);
      pB[j] += 64;
    }
    __syncthreads();
#pragma unroll
    for (int s = 0; s < 2; ++s) {
      const int sq = s ? sq1 : sq0;
      f16x8 av[4], bv[4];
#pragma unroll
      for (int i = 0; i < 4; ++i) {
        av[i] = *(const f16x8*)((const char*)lA + (aoffx[i] ^ sq));
        bv[i] = *(const f16x8*)((const char*)lB + (boffx[i] ^ sq));
      }
#pragma unroll
      for (int mi = 0; mi < 4; ++mi)
#pragma unroll
        for (int ni = 0; ni < 4; ++ni)
          acc[mi][ni] = __builtin_amdgcn_mfma_f32_16x16x32_f16(av[mi], bv[ni], acc[mi][ni], 0, 0, 0);
    }
    __syncthreads();
  }

  int rl[4], cl[4];
#pragma unroll
  for (int e = 0; e < 4; ++e) {
    rl[e] = rmap[lane * 4 + e];
    cl[e] = cmap[lane * 4 + e];
  }
#pragma unroll
  for (int mi = 0; mi < 4; ++mi)
#pragma unroll
    for (int e = 0; e < 4; ++e) {
      const int rloc = wm + mi * 16 + rl[e];
      const int row = bm + rloc;
      float s = 0.f;
#pragma unroll
      for (int ni = 0; ni < 4; ++ni) {
        float p = __expf(acc[mi][ni][e] - 100.0f);
        s += p;
        P[(size_t)row * N + (bn + wn + ni * 16 + cl[e])] = f2bf(p);
      }
      s += __shfl_xor(s, 1, 64);
      s += __shfl_xor(s, 2, 64);
      s += __shfl_xor(s, 4, 64);
      s += __shfl_xor(s, 8, 64);
      if (t == 0) lrs[rloc][wave >> 2] = s;
    }
  __syncthreads();
  if (tid < 256)
    rsp[(size_t)blockIdx.x * 8192 + bm + tid] = lrs[tid][0] + lrs[tid][1];
}

__global__ __launch_bounds__(256) void finalize_invl(
    const float* __restrict__ rsp, float* __restrict__ invl) {
  const int row = blockIdx.x * 256 + threadIdx.x;
  float s = 0.f;
#pragma unroll 8
  for (int b = 0; b < 64; ++b) s += rsp[(size_t)b * 8192 + row];
  invl[row] = 1.0f / s;
}

// ---------------------------------------------------------------------------
// NT GEMM 128x128, BK=64, swizzled LDS; F16 selects f16 MFMA. (r9, proven)
// ---------------------------------------------------------------------------
template <int EPI, int F16>
__global__ __launch_bounds__(256) void gemm_nt(
    const u16* __restrict__ A, const u16* __restrict__ B, int K, int Kc, int N,
    u16* __restrict__ outp, const float* __restrict__ invl,
    const int* __restrict__ rmap, const int* __restrict__ cmap) {
  __shared__ __align__(16) u16 lA[128 * 64];
  __shared__ __align__(16) u16 lB[128 * 64];

  const int tid = threadIdx.x;
  const int wave = tid >> 6, lane = tid & 63;
  const int quad = lane >> 4, t = lane & 15;
  const int bm = blockIdx.y * 128, bn = blockIdx.x * 128;
  const int wm = (wave & 1) * 64, wn = (wave >> 1) * 64;
  const int koff = blockIdx.z * Kc;

  f32x4 acc[4][4];
#pragma unroll
  for (int i = 0; i < 4; ++i)
#pragma unroll
    for (int j = 0; j < 4; ++j) acc[i][j] = (f32x4){0.f, 0.f, 0.f, 0.f};

  const int srow = tid >> 3, schk = tid & 7;
  const u16* pA[4]; const u16* pB[4];
#pragma unroll
  for (int j = 0; j < 4; ++j) {
    const int r = j * 32 + srow;
    const int c = schk ^ swz8(r);
    pA[j] = A + (size_t)(bm + r) * K + koff + c * 8;
    pB[j] = B + (size_t)(bn + r) * K + koff + c * 8;
  }

  int aoffx[4], boffx[4];
#pragma unroll
  for (int i = 0; i < 4; ++i) {
    const int rm = wm + i * 16 + t;
    aoffx[i] = rm * 128 + (swz8(rm) << 4);
    const int rn = wn + i * 16 + t;
    boffx[i] = rn * 128 + (swz8(rn) << 4);
  }
  const int sq0 = quad << 4, sq1 = (quad << 4) | 64;

  for (int k0 = 0; k0 < Kc; k0 += 64) {
#pragma unroll
    for (int j = 0; j < 4; ++j) {
      async16(pA[j], (char*)lA + j * 4096 + wave * 1024);
      async16(pB[j], (char*)lB + j * 4096 + wave * 1024);
      pA[j] += 64; pB[j] += 64;
    }
    __syncthreads();
#pragma unroll
    for (int s = 0; s < 2; ++s) {
      const int sq = s ? sq1 : sq0;
      bf16x8 av[4], bv[4];
#pragma unroll
      for (int i = 0; i < 4; ++i) {
        av[i] = *(const bf16x8*)((const char*)lA + (aoffx[i] ^ sq));
        bv[i] = *(const bf16x8*)((const char*)lB + (boffx[i] ^ sq));
      }
#pragma unroll
      for (int mi = 0; mi < 4; ++mi)
#pragma unroll
        for (int ni = 0; ni < 4; ++ni) {
          if constexpr (F16)
            acc[mi][ni] = __builtin_amdgcn_mfma_f32_16x16x32_f16(
                __builtin_bit_cast(f16x8, av[mi]), __builtin_bit_cast(f16x8, bv[ni]),
                acc[mi][ni], 0, 0, 0);
          else
            acc[mi][ni] = __builtin_amdgcn_mfma_f32_16x16x32_bf16(av[mi], bv[ni], acc[mi][ni], 0, 0, 0);
        }
    }
    __syncthreads();
  }

  int rl[4], cl[4];
#pragma unroll
  for (int e = 0; e < 4; ++e) {
    rl[e] = rmap[lane * 4 + e];
    cl[e] = cmap[lane * 4 + e];
  }
  const size_t zoff = (size_t)blockIdx.z * ((size_t)gridDim.y * 128) * N;
#pragma unroll
  for (int mi = 0; mi < 4; ++mi)
#pragma unroll
    for (int e = 0; e < 4; ++e) {
      const int row = bm + wm + mi * 16 + rl[e];
      const float sc = (EPI == EPI_PARTH) ? invl[row] : 1.0f;
#pragma unroll
      for (int ni = 0; ni < 4; ++ni) {
        const size_t idx = (size_t)row * N + (bn + wn + ni * 16 + cl[e]);
        if (EPI == EPI_PARTH) outp[zoff + idx] = f2h(acc[mi][ni][e] * sc);
        else                  outp[idx] = f2bf(acc[mi][ni][e]);
      }
    }
}

// ---------------------------------------------------------------------------
__global__ __launch_bounds__(256) void combine1(
    const u16* __restrict__ pp, const float* __restrict__ invl,
    float* __restrict__ x1f, u16* __restrict__ x1h) {
  const int row = blockIdx.x, j = threadIdx.x;
  const size_t i = (size_t)row * 256 + j;
  const float v = h2f(pp[i]) + h2f(pp[2097152 + i]) +
                  h2f(pp[4194304 + i]) + h2f(pp[6291456 + i]);
  x1f[i] = v;
  x1h[i] = f2bf(v);
}

__global__ __launch_bounds__(128) void combine2(
    const u16* __restrict__ pp, const float* __restrict__ invl,
    float* __restrict__ x2f) {
  const int row = blockIdx.x, j = threadIdx.x;
  const size_t i = (size_t)row * 128 + j;
  float s = 0.f;
#pragma unroll
  for (int z = 0; z < 8; ++z) s += h2f(pp[(size_t)z * 1048576 + i]);
  x2f[i] = s;
}

// ---------------------------------------------------------------------------
extern "C" void kernel_launch(void* const* d_in, const int* in_sizes, int n_in,
                              void* d_out, int out_size, void* d_ws, size_t ws_size,
                              hipStream_t stream) {
  const float* Fs = (const float*)d_in[0];   // [8192][512]
  const float* Ft = (const float*)d_in[1];   // [8192][512]
  const float* W1 = (const float*)d_in[2];   // [256][512]
  const float* W2 = (const float*)d_in[3];   // [128][256]

  char* ws = (char*)d_ws;                    // extent <= 168134656 (proven r5-r9)
  u16*   P    = (u16*)(ws);                  // [8192][8192] bf16, 0..128MiB
  u16*   Fsf  = (u16*)(ws + 134217728);      // 8MiB f16 (dead after GY1)
  u16*   Ftf  = (u16*)(ws + 142606336);      // 8MiB f16 (dead after G2)
  u16*   pp   = (u16*)(ws + 134217728);      // 16MiB f16 partials (born F1)
  float* rsp  = (float*)(ws + 150994944);    // [64][8192] f32 2MiB (dead after FIN)
  u16*   Y1T  = (u16*)(ws + 153091200);      // [256][8192] 4MiB
  u16*   x1h  = (u16*)(ws + 157286400);      // [8192][256] 4MiB
  u16*   Y2T  = (u16*)(ws + 161480704);      // [128][8192] 2MiB
  float* invl = (float*)(ws + 163577856);    // [8192]
  int*   rmap = (int*)  (ws + 163610624);
  int*   cmap = (int*)  (ws + 163611648);
  u16*   W1f  = (u16*)(ws + 163612672);      // [256][512] f16 256KiB
  u16*   W2h  = (u16*)(ws + 163874816);      // [128][256] bf16 64KiB -> 163938816

  float* x1f = (float*)d_out;                // [8192][256]
  float* x2f = (float*)d_out + 2097152;      // [8192][128]

  dim3 blk(256);
  probe_layout<<<1, 64, 0, stream>>>(rmap, cmap);
  conv_all<<<4176, blk, 0, stream>>>(Fs, Ft, W1, W2, Fsf, Ftf, W1f, W2h);
  // G2: P~ = exp(f16 S - 100) + fused row-sum partials (256x128 tile)
  gemm_pexp_f16_256<<<dim3(64, 32), dim3(512), 0, stream>>>(
      Fsf, Ftf, 512, 8192, P, rsp, rmap, cmap);
  finalize_invl<<<32, blk, 0, stream>>>(rsp, invl);
  // GY1: Y1T = W1f @ Fsf^T (f16)
  gemm_nt<EPI_STOREB, 1><<<dim3(64, 2), blk, 0, stream>>>(
      W1f, Fsf, 512, 512, 8192, Y1T, nullptr, rmap, cmap);
  // F1: pp[z] = invl(.)(P~ @ Y1), split-K=4 (Kc=2048), 512 blocks = 2/CU
  gemm_nt<EPI_PARTH, 0><<<dim3(2, 64, 4), blk, 0, stream>>>(
      P, Y1T, 8192, 2048, 256, pp, invl, rmap, cmap);
  combine1<<<8192, blk, 0, stream>>>(pp, invl, x1f, x1h);
  // GY2: Y2T = W2h @ x1h^T (bf16)
  gemm_nt<EPI_STOREB, 0><<<dim3(64, 1), blk, 0, stream>>>(
      W2h, x1h, 256, 256, 8192, Y2T, nullptr, rmap, cmap);
  // F2: pp[z] = invl(.)(P~ @ Y2), split-K=8 (Kc=1024), 512 blocks = 2/CU
  gemm_nt<EPI_PARTH, 0><<<dim3(1, 64, 8), blk, 0, stream>>>(
      P, Y2T, 8192, 1024, 128, pp, invl, rmap, cmap);
  combine2<<<8192, dim3(128), 0, stream>>>(pp, invl, x2f);
}